// Round 1
// baseline (60.599 us; speedup 1.0000x reference)
//
#include <hip/hip_runtime.h>
#include <hip/hip_bf16.h>

typedef __attribute__((ext_vector_type(8))) short short8;
typedef __attribute__((ext_vector_type(4))) float f32x4;

#define LOG2E 1.4426950408889634f
#define BM 128
#define BN 128
#define SPLITS 128
#define NTOT 65536
#define BTOT 2048
#define NCHUNK (NTOT / SPLITS)   /* 512 */
#define NITER (NCHUNK / BN)      /* 4 */

__device__ __forceinline__ unsigned short f2bf(float f) {
    union { __hip_bfloat16 h; unsigned short u; } c;
    c.h = __float2bfloat16(f);
    return c.u;
}

// Swizzled LDS byte offset for a [row][128B] bf16 tile: XOR k-block with row
// bits so ds_read_b128 of a column-slice spreads across all 32 banks.
__device__ __forceinline__ int swz(int row, int kbyte) {
    return row * 128 + (kbyte ^ ((row & 7) << 4));
}

// per-row squared-norm * (-scale*log2e): 16 threads per row, float4 loads.
__global__ void kde_rownorm(const float* __restrict__ in,
                            const float* __restrict__ scale_p,
                            float* __restrict__ out, int nrows) {
    int t = blockIdx.x * 256 + threadIdx.x;
    int row = t >> 4;
    if (row >= nrows) return;
    int c4 = t & 15;
    float4 v = *(const float4*)&in[(size_t)row * 64 + c4 * 4];
    float ss = v.x * v.x + v.y * v.y + v.z * v.z + v.w * v.w;
    ss += __shfl_xor(ss, 1, 64);
    ss += __shfl_xor(ss, 2, 64);
    ss += __shfl_xor(ss, 4, 64);
    ss += __shfl_xor(ss, 8, 64);
    if (c4 == 0) out[row] = -scale_p[0] * LOG2E * ss;
}

__global__ __launch_bounds__(256) void kde_main(
    const float* __restrict__ X, const float* __restrict__ svs,
    const float* __restrict__ scale_p, const float* __restrict__ a2,
    const float* __restrict__ b2, float* __restrict__ partials) {
    __shared__ __align__(16) unsigned char ldsA[BM * 128];
    __shared__ __align__(16) unsigned char ldsB[BN * 128];

    const int tid = threadIdx.x;
    const int lane = tid & 63;
    const int wave = tid >> 6;
    const int mtile = blockIdx.x;    // 0..15
    const int nsplit = blockIdx.y;   // 0..SPLITS-1
    const int rowbase = mtile * BM;
    const int nbase = nsplit * NCHUNK;
    const float C1 = 2.0f * scale_p[0] * LOG2E;

    // ---- stage A tile: 128 rows x 64 k, f32 -> bf16, swizzled ----
    {
        int r16 = tid >> 4, c4 = tid & 15;
        for (int p = 0; p < 8; ++p) {
            int row = p * 16 + r16;
            float4 v = *(const float4*)&X[(size_t)(rowbase + row) * 64 + c4 * 4];
            uint2 pk;
            pk.x = (unsigned)f2bf(v.x) | ((unsigned)f2bf(v.y) << 16);
            pk.y = (unsigned)f2bf(v.z) | ((unsigned)f2bf(v.w) << 16);
            *(uint2*)(ldsA + swz(row, c4 * 8)) = pk;
        }
    }
    __syncthreads();

    // ---- A fragments (K=64 fully resident): rows wave*32 + mf*16 + (lane&15)
    short8 afrag[2][2];
    {
        int arow = wave * 32 + (lane & 15);
        int kb = (lane >> 4) * 16;
        for (int mf = 0; mf < 2; ++mf)
            for (int kf = 0; kf < 2; ++kf)
                afrag[mf][kf] =
                    *(const short8*)(ldsA + swz(arow + mf * 16, kb + kf * 64));
    }
    // a2 for the C-layout rows this lane owns: row = (lane>>4)*4 + j
    float a2l[2][4];
    for (int mf = 0; mf < 2; ++mf)
        for (int j = 0; j < 4; ++j)
            a2l[mf][j] = a2[rowbase + wave * 32 + mf * 16 + (lane >> 4) * 4 + j];

    float s[2][4] = {{0.f, 0.f, 0.f, 0.f}, {0.f, 0.f, 0.f, 0.f}};

    for (int it = 0; it < NITER; ++it) {
        int nb0 = nbase + it * BN;
        __syncthreads();  // ldsB consumed by previous iteration
        {
            int r16 = tid >> 4, c4 = tid & 15;
            for (int p = 0; p < 8; ++p) {
                int row = p * 16 + r16;
                float4 v = *(const float4*)&svs[(size_t)(nb0 + row) * 64 + c4 * 4];
                uint2 pk;
                pk.x = (unsigned)f2bf(v.x) | ((unsigned)f2bf(v.y) << 16);
                pk.y = (unsigned)f2bf(v.z) | ((unsigned)f2bf(v.w) << 16);
                *(uint2*)(ldsB + swz(row, c4 * 8)) = pk;
            }
        }
        float b2l[8];
        for (int nf = 0; nf < 8; ++nf)
            b2l[nf] = b2[nb0 + nf * 16 + (lane & 15)];
        __syncthreads();

        for (int nf = 0; nf < 8; ++nf) {
            int brow = nf * 16 + (lane & 15);
            int kb = (lane >> 4) * 16;
            short8 b0 = *(const short8*)(ldsB + swz(brow, kb));
            short8 b1 = *(const short8*)(ldsB + swz(brow, kb + 64));
            for (int mf = 0; mf < 2; ++mf) {
                f32x4 acc = {0.f, 0.f, 0.f, 0.f};
                acc = __builtin_amdgcn_mfma_f32_16x16x32_bf16(afrag[mf][0], b0,
                                                              acc, 0, 0, 0);
                acc = __builtin_amdgcn_mfma_f32_16x16x32_bf16(afrag[mf][1], b1,
                                                              acc, 0, 0, 0);
                for (int j = 0; j < 4; ++j) {
                    float e = __builtin_fmaf(C1, acc[j], a2l[mf][j]) + b2l[nf];
                    s[mf][j] += __builtin_amdgcn_exp2f(e);
                }
            }
        }
    }

    // reduce partial sums across the 16 lanes holding the same rows
    for (int mask = 1; mask < 16; mask <<= 1)
        for (int mf = 0; mf < 2; ++mf)
            for (int j = 0; j < 4; ++j)
                s[mf][j] += __shfl_xor(s[mf][j], mask, 64);

    if ((lane & 15) == 0) {
        for (int mf = 0; mf < 2; ++mf)
            for (int j = 0; j < 4; ++j) {
                int row = rowbase + wave * 32 + mf * 16 + (lane >> 4) * 4 + j;
                partials[(size_t)nsplit * BTOT + row] = s[mf][j];
            }
    }
}

__global__ void kde_final(const float* __restrict__ partials,
                          const float* __restrict__ scale_p,
                          float* __restrict__ out) {
    int b = blockIdx.x * 256 + threadIdx.x;
    if (b >= BTOT) return;
    float total = 0.f;
    for (int sidx = 0; sidx < SPLITS; ++sidx)
        total += partials[(size_t)sidx * BTOT + b];
    float scale = scale_p[0];
    out[b] = logf(total) - logf((float)NTOT) +
             32.0f * logf(scale / 3.14159265358979323846f);
}

extern "C" void kernel_launch(void* const* d_in, const int* in_sizes, int n_in,
                              void* d_out, int out_size, void* d_ws,
                              size_t ws_size, hipStream_t stream) {
    const float* X = (const float*)d_in[0];
    const float* svs = (const float*)d_in[1];
    const float* scale_p = (const float*)d_in[2];
    float* ws = (float*)d_ws;
    float* b2 = ws;                       // 65536 f32
    float* a2 = ws + NTOT;                // 2048 f32
    float* partials = ws + NTOT + BTOT;   // SPLITS*2048 f32

    kde_rownorm<<<(NTOT * 16) / 256, 256, 0, stream>>>(svs, scale_p, b2, NTOT);
    kde_rownorm<<<(BTOT * 16) / 256, 256, 0, stream>>>(X, scale_p, a2, BTOT);
    dim3 grid(BTOT / BM, SPLITS);
    kde_main<<<grid, 256, 0, stream>>>(X, svs, scale_p, a2, b2, partials);
    kde_final<<<BTOT / 256, 256, 0, stream>>>(partials, scale_p, (float*)d_out);
}

// Round 2
// 44.598 us; speedup vs baseline: 1.3588x; 1.3588x over previous
//
#include <hip/hip_runtime.h>
#include <hip/hip_bf16.h>

typedef __attribute__((ext_vector_type(8))) short short8;
typedef __attribute__((ext_vector_type(4))) float f32x4;

#define LOG2E 1.4426950408889634f
#define PI_F 3.14159265358979323846f
#define NTOT 65536
#define BTOT 2048
#define DIM 64
#define SPLITS 64
#define NITER 8          /* tiles of 128 svs-rows per split */
#define NTILES 512       /* NTOT / 128 */

/* ws layout (bytes) */
#define OFF_SVSBF 0u
#define OFF_XBF   8388608u
#define OFF_B2    8650752u
#define OFF_A2    8912896u
#define OFF_PART  8921088u
#define WS_NEEDED 9445376u

__device__ __forceinline__ unsigned short f2bf(float f) {
    union { __hip_bfloat16 h; unsigned short u; } c;
    c.h = __float2bfloat16(f);
    return c.u;
}

// byte offset into a [row][128B] bf16 tile, XOR-swizzled so ds_read_b128 of a
// column slice is bank-conflict-free.
__device__ __forceinline__ int swz(int row, int kbyte) {
    return row * 128 + (kbyte ^ ((row & 7) << 4));
}

// ---------------- prepass: f32 -> bf16 (+norms) ----------------
// blocks 0..511: svs tile -> swizzled-layout bf16 + b2 = -scale*log2e*||y||^2
// blocks 512..527: X tile -> C1-prescaled bf16 (row-major) + a2 = -scale*||x||^2
__global__ __launch_bounds__(256) void kde_prep(
    const float* __restrict__ X, const float* __restrict__ svs,
    const float* __restrict__ scale_p, unsigned short* __restrict__ svs_bf,
    unsigned short* __restrict__ x_bf, float* __restrict__ b2,
    float* __restrict__ a2nat) {
    const float scale = scale_p[0];
    const int tid = threadIdx.x;
    const int blk = blockIdx.x;
    if (blk < NTILES) {
        for (int i = 0; i < 4; ++i) {
            int g = i * 256 + tid;
            int row = g >> 3, grp = g & 7;
            const float* src = svs + ((size_t)blk * 128 + row) * DIM + grp * 8;
            float4 v0 = *(const float4*)src;
            float4 v1 = *(const float4*)(src + 4);
            float ss = v0.x * v0.x + v0.y * v0.y + v0.z * v0.z + v0.w * v0.w +
                       v1.x * v1.x + v1.y * v1.y + v1.z * v1.z + v1.w * v1.w;
            short8 o;
            o[0] = f2bf(v0.x); o[1] = f2bf(v0.y); o[2] = f2bf(v0.z); o[3] = f2bf(v0.w);
            o[4] = f2bf(v1.x); o[5] = f2bf(v1.y); o[6] = f2bf(v1.z); o[7] = f2bf(v1.w);
            int dgrp = grp ^ (row & 7);
            *(short8*)(svs_bf + (size_t)blk * 8192 + row * 64 + dgrp * 8) = o;
            ss += __shfl_xor(ss, 1, 64);
            ss += __shfl_xor(ss, 2, 64);
            ss += __shfl_xor(ss, 4, 64);
            if (grp == 0) b2[blk * 128 + row] = -scale * LOG2E * ss;
        }
    } else {
        const int t16 = blk - NTILES;
        const float C1 = 2.0f * scale * LOG2E;
        for (int i = 0; i < 4; ++i) {
            int g = i * 256 + tid;
            int row = g >> 3, grp = g & 7;
            const float* src = X + ((size_t)t16 * 128 + row) * DIM + grp * 8;
            float4 v0 = *(const float4*)src;
            float4 v1 = *(const float4*)(src + 4);
            float ss = v0.x * v0.x + v0.y * v0.y + v0.z * v0.z + v0.w * v0.w +
                       v1.x * v1.x + v1.y * v1.y + v1.z * v1.z + v1.w * v1.w;
            short8 o;
            o[0] = f2bf(v0.x * C1); o[1] = f2bf(v0.y * C1);
            o[2] = f2bf(v0.z * C1); o[3] = f2bf(v0.w * C1);
            o[4] = f2bf(v1.x * C1); o[5] = f2bf(v1.y * C1);
            o[6] = f2bf(v1.z * C1); o[7] = f2bf(v1.w * C1);
            *(short8*)(x_bf + ((size_t)t16 * 128 + row) * 64 + grp * 8) = o;
            ss += __shfl_xor(ss, 1, 64);
            ss += __shfl_xor(ss, 2, 64);
            ss += __shfl_xor(ss, 4, 64);
            if (grp == 0) a2nat[t16 * 128 + row] = -scale * ss;
        }
    }
}

// ---------------- main: MFMA + fused exp2-sum ----------------
__global__ __launch_bounds__(256) void kde_main2(
    const unsigned short* __restrict__ svs_bf,
    const unsigned short* __restrict__ x_bf, const float* __restrict__ b2,
    float* __restrict__ partials) {
    __shared__ __align__(16) unsigned char ldsB[2][16384];
    __shared__ __align__(16) float ldsb2[1024];

    const int tid = threadIdx.x, lane = tid & 63, wave = tid >> 6;
    const int mtile = blockIdx.x, nsplit = blockIdx.y;
    const int rowbase = mtile * 128;
    const int col = lane & 15, krow = lane >> 4;

    // A fragments direct from global (prescaled bf16, row-major)
    short8 afrag[2][2];
    {
        int arow = rowbase + wave * 32 + col;
        for (int mf = 0; mf < 2; ++mf)
            for (int kf = 0; kf < 2; ++kf)
                afrag[mf][kf] = *(const short8*)(x_bf + (size_t)(arow + mf * 16) * 64 +
                                                 krow * 8 + kf * 32);
    }
    // drain afrag loads so the vmcnt ledger below is exact
    asm volatile("s_waitcnt vmcnt(0)" ::: "memory");

    // stage b2 chunk (1024 f32) then first two svs tiles, all via global_load_lds
    {
        const float* gb2 = b2 + nsplit * 1024 + wave * 256 + lane * 4;
        __builtin_amdgcn_global_load_lds(
            (const __attribute__((address_space(1))) void*)gb2,
            (__attribute__((address_space(3))) void*)&ldsb2[wave * 256], 16, 0, 0);
    }
    const unsigned char* gsv =
        (const unsigned char*)svs_bf + (size_t)nsplit * NITER * 16384;
#define ISSUE_TILE(t_, buf_)                                                      \
    do {                                                                          \
        const unsigned char* gt =                                                 \
            gsv + (size_t)(t_)*16384 + (size_t)wave * 4096 + lane * 16;           \
        for (int ii = 0; ii < 4; ++ii)                                            \
            __builtin_amdgcn_global_load_lds(                                     \
                (const __attribute__((address_space(1))) void*)(gt + ii * 1024),  \
                (__attribute__((address_space(3))) void*)&ldsB[buf_][(wave * 4 + ii) * 1024], \
                16, 0, 0);                                                        \
    } while (0)
    ISSUE_TILE(0, 0);
    ISSUE_TILE(1, 1);

    float s[2][4] = {{0.f, 0.f, 0.f, 0.f}, {0.f, 0.f, 0.f, 0.f}};

#pragma unroll
    for (int it = 0; it < NITER; ++it) {
        if (it < NITER - 1)
            asm volatile("s_waitcnt vmcnt(4)" ::: "memory");  // tile it landed
        else
            asm volatile("s_waitcnt vmcnt(0)" ::: "memory");
        asm volatile("s_barrier" ::: "memory");  // all waves' quarters visible
        const unsigned char* buf = ldsB[it & 1];
#pragma unroll
        for (int nf = 0; nf < 8; ++nf) {
            float b2l = ldsb2[it * 128 + nf * 16 + col];
            int brow = nf * 16 + col;
            int kb = krow * 16;
            short8 bb0 = *(const short8*)(buf + swz(brow, kb));
            short8 bb1 = *(const short8*)(buf + swz(brow, kb + 64));
#pragma unroll
            for (int mf = 0; mf < 2; ++mf) {
                f32x4 acc = {b2l, b2l, b2l, b2l};  // bias folded into C-init
                acc = __builtin_amdgcn_mfma_f32_16x16x32_bf16(afrag[mf][0], bb0,
                                                              acc, 0, 0, 0);
                acc = __builtin_amdgcn_mfma_f32_16x16x32_bf16(afrag[mf][1], bb1,
                                                              acc, 0, 0, 0);
                s[mf][0] += __builtin_amdgcn_exp2f(acc[0]);
                s[mf][1] += __builtin_amdgcn_exp2f(acc[1]);
                s[mf][2] += __builtin_amdgcn_exp2f(acc[2]);
                s[mf][3] += __builtin_amdgcn_exp2f(acc[3]);
            }
        }
        asm volatile("s_barrier" ::: "memory");  // buf fully consumed by all
        if (it + 2 < NITER) ISSUE_TILE(it + 2, it & 1);
    }
#undef ISSUE_TILE

    for (int mask = 1; mask < 16; mask <<= 1)
        for (int mf = 0; mf < 2; ++mf)
            for (int j = 0; j < 4; ++j)
                s[mf][j] += __shfl_xor(s[mf][j], mask, 64);

    if (col == 0) {
        for (int mf = 0; mf < 2; ++mf)
            for (int j = 0; j < 4; ++j) {
                int row = rowbase + wave * 32 + mf * 16 + krow * 4 + j;
                partials[(size_t)nsplit * BTOT + row] = s[mf][j];
            }
    }
}

__global__ void kde_final2(const float* __restrict__ partials,
                           const float* __restrict__ a2nat,
                           const float* __restrict__ scale_p,
                           float* __restrict__ out) {
    int b = blockIdx.x * 256 + threadIdx.x;
    if (b >= BTOT) return;
    float total = 0.f;
    for (int sidx = 0; sidx < SPLITS; ++sidx)
        total += partials[(size_t)sidx * BTOT + b];
    out[b] = logf(total) + a2nat[b] - logf((float)NTOT) +
             32.0f * logf(scale_p[0] / PI_F);
}

// ================= fallback path (round-1, proven) =================
__global__ void fb_rownorm(const float* __restrict__ in,
                           const float* __restrict__ scale_p,
                           float* __restrict__ out, int nrows) {
    int t = blockIdx.x * 256 + threadIdx.x;
    int row = t >> 4;
    if (row >= nrows) return;
    int c4 = t & 15;
    float4 v = *(const float4*)&in[(size_t)row * 64 + c4 * 4];
    float ss = v.x * v.x + v.y * v.y + v.z * v.z + v.w * v.w;
    ss += __shfl_xor(ss, 1, 64);
    ss += __shfl_xor(ss, 2, 64);
    ss += __shfl_xor(ss, 4, 64);
    ss += __shfl_xor(ss, 8, 64);
    if (c4 == 0) out[row] = -scale_p[0] * LOG2E * ss;
}

__global__ __launch_bounds__(256) void fb_main(
    const float* __restrict__ X, const float* __restrict__ svs,
    const float* __restrict__ scale_p, const float* __restrict__ a2,
    const float* __restrict__ b2, float* __restrict__ partials) {
    __shared__ __align__(16) unsigned char ldsA[128 * 128];
    __shared__ __align__(16) unsigned char ldsBf[128 * 128];
    const int tid = threadIdx.x, lane = tid & 63, wave = tid >> 6;
    const int rowbase = blockIdx.x * 128, nbase = blockIdx.y * 512;
    const float C1 = 2.0f * scale_p[0] * LOG2E;
    {
        int r16 = tid >> 4, c4 = tid & 15;
        for (int p = 0; p < 8; ++p) {
            int row = p * 16 + r16;
            float4 v = *(const float4*)&X[(size_t)(rowbase + row) * 64 + c4 * 4];
            uint2 pk;
            pk.x = (unsigned)f2bf(v.x) | ((unsigned)f2bf(v.y) << 16);
            pk.y = (unsigned)f2bf(v.z) | ((unsigned)f2bf(v.w) << 16);
            *(uint2*)(ldsA + swz(row, c4 * 8)) = pk;
        }
    }
    __syncthreads();
    short8 afrag[2][2];
    {
        int arow = wave * 32 + (lane & 15);
        int kb = (lane >> 4) * 16;
        for (int mf = 0; mf < 2; ++mf)
            for (int kf = 0; kf < 2; ++kf)
                afrag[mf][kf] = *(const short8*)(ldsA + swz(arow + mf * 16, kb + kf * 64));
    }
    float a2l[2][4];
    for (int mf = 0; mf < 2; ++mf)
        for (int j = 0; j < 4; ++j)
            a2l[mf][j] = a2[rowbase + wave * 32 + mf * 16 + (lane >> 4) * 4 + j];
    float s[2][4] = {{0.f, 0.f, 0.f, 0.f}, {0.f, 0.f, 0.f, 0.f}};
    for (int itq = 0; itq < 4; ++itq) {
        int nb0 = nbase + itq * 128;
        __syncthreads();
        {
            int r16 = tid >> 4, c4 = tid & 15;
            for (int p = 0; p < 8; ++p) {
                int row = p * 16 + r16;
                float4 v = *(const float4*)&svs[(size_t)(nb0 + row) * 64 + c4 * 4];
                uint2 pk;
                pk.x = (unsigned)f2bf(v.x) | ((unsigned)f2bf(v.y) << 16);
                pk.y = (unsigned)f2bf(v.z) | ((unsigned)f2bf(v.w) << 16);
                *(uint2*)(ldsBf + swz(row, c4 * 8)) = pk;
            }
        }
        float b2l[8];
        for (int nf = 0; nf < 8; ++nf)
            b2l[nf] = b2[nb0 + nf * 16 + (lane & 15)];
        __syncthreads();
        for (int nf = 0; nf < 8; ++nf) {
            int brow = nf * 16 + (lane & 15);
            int kb = (lane >> 4) * 16;
            short8 b0 = *(const short8*)(ldsBf + swz(brow, kb));
            short8 b1 = *(const short8*)(ldsBf + swz(brow, kb + 64));
            for (int mf = 0; mf < 2; ++mf) {
                f32x4 acc = {0.f, 0.f, 0.f, 0.f};
                acc = __builtin_amdgcn_mfma_f32_16x16x32_bf16(afrag[mf][0], b0, acc, 0, 0, 0);
                acc = __builtin_amdgcn_mfma_f32_16x16x32_bf16(afrag[mf][1], b1, acc, 0, 0, 0);
                for (int j = 0; j < 4; ++j) {
                    float e = __builtin_fmaf(C1, acc[j], a2l[mf][j]) + b2l[nf];
                    s[mf][j] += __builtin_amdgcn_exp2f(e);
                }
            }
        }
    }
    for (int mask = 1; mask < 16; mask <<= 1)
        for (int mf = 0; mf < 2; ++mf)
            for (int j = 0; j < 4; ++j)
                s[mf][j] += __shfl_xor(s[mf][j], mask, 64);
    if ((lane & 15) == 0) {
        for (int mf = 0; mf < 2; ++mf)
            for (int j = 0; j < 4; ++j) {
                int row = rowbase + wave * 32 + mf * 16 + (lane >> 4) * 4 + j;
                partials[(size_t)blockIdx.y * BTOT + row] = s[mf][j];
            }
    }
}

__global__ void fb_final(const float* __restrict__ partials,
                         const float* __restrict__ scale_p,
                         float* __restrict__ out) {
    int b = blockIdx.x * 256 + threadIdx.x;
    if (b >= BTOT) return;
    float total = 0.f;
    for (int sidx = 0; sidx < 128; ++sidx)
        total += partials[(size_t)sidx * BTOT + b];
    out[b] = logf(total) - logf((float)NTOT) + 32.0f * logf(scale_p[0] / PI_F);
}

extern "C" void kernel_launch(void* const* d_in, const int* in_sizes, int n_in,
                              void* d_out, int out_size, void* d_ws,
                              size_t ws_size, hipStream_t stream) {
    const float* X = (const float*)d_in[0];
    const float* svs = (const float*)d_in[1];
    const float* scale_p = (const float*)d_in[2];
    unsigned char* ws = (unsigned char*)d_ws;

    if (ws_size >= WS_NEEDED) {
        unsigned short* svs_bf = (unsigned short*)(ws + OFF_SVSBF);
        unsigned short* x_bf = (unsigned short*)(ws + OFF_XBF);
        float* b2 = (float*)(ws + OFF_B2);
        float* a2nat = (float*)(ws + OFF_A2);
        float* partials = (float*)(ws + OFF_PART);
        kde_prep<<<NTILES + 16, 256, 0, stream>>>(X, svs, scale_p, svs_bf, x_bf,
                                                  b2, a2nat);
        dim3 grid(BTOT / 128, SPLITS);
        kde_main2<<<grid, 256, 0, stream>>>(svs_bf, x_bf, b2, partials);
        kde_final2<<<BTOT / 256, 256, 0, stream>>>(partials, a2nat, scale_p,
                                                   (float*)d_out);
    } else {
        float* wsf = (float*)d_ws;
        float* b2 = wsf;
        float* a2 = wsf + NTOT;
        float* partials = wsf + NTOT + BTOT;
        fb_rownorm<<<(NTOT * 16) / 256, 256, 0, stream>>>(svs, scale_p, b2, NTOT);
        fb_rownorm<<<(BTOT * 16) / 256, 256, 0, stream>>>(X, scale_p, a2, BTOT);
        dim3 grid(BTOT / 128, 128);
        fb_main<<<grid, 256, 0, stream>>>(X, svs, scale_p, a2, b2, partials);
        fb_final<<<BTOT / 256, 256, 0, stream>>>(partials, scale_p, (float*)d_out);
    }
}